// Round 8
// baseline (248.833 us; speedup 1.0000x reference)
//
#include <hip/hip_runtime.h>

#define DDIM 256
#define NTOK 4096   // B*S = 64*64
#define NEGN 8192
// small 64x64 kernel (fr alignment)
#define TM 64
#define TN 64
#define LDT 40      // padded halfs per LDS row for the small kernel

typedef __attribute__((ext_vector_type(8))) short bf16x8;
typedef __attribute__((ext_vector_type(4))) float f32x4;

__device__ inline unsigned short f2bf(float f) {
    unsigned int u = __float_as_uint(f);
    unsigned int r = u + 0x7FFFu + ((u >> 16) & 1u);
    return (unsigned short)(r >> 16);
}

// global->LDS direct DMA, 16B/lane; LDS dest = wave-uniform base + lane*16.
__device__ inline void gl_lds16(const unsigned short* g, unsigned short* l) {
    __builtin_amdgcn_global_load_lds(
        reinterpret_cast<__attribute__((address_space(1))) unsigned int*>(
            reinterpret_cast<uintptr_t>(g)),
        reinterpret_cast<__attribute__((address_space(3))) unsigned int*>(
            reinterpret_cast<uintptr_t>(l)),
        16, 0, 0);
}

__device__ inline void wait_vmcnt8() { asm volatile("s_waitcnt vmcnt(8)" ::: "memory"); }
__device__ inline void wait_vmcnt4() { asm volatile("s_waitcnt vmcnt(4)" ::: "memory"); }
__device__ inline void wait_vmcnt0() { asm volatile("s_waitcnt vmcnt(0)" ::: "memory"); }

// DPP 16-lane sum reduction — VALU only.
template<int CTRL>
__device__ inline float dpp_add(float x) {
    int v = __builtin_amdgcn_update_dpp(0, __float_as_int(x), CTRL, 0xF, 0xF, false);
    return x + __int_as_float(v);
}
__device__ inline float red16(float x) {
    x = dpp_add<0xB1>(x);    // quad_perm [1,0,3,2]
    x = dpp_add<0x4E>(x);    // quad_perm [2,3,0,1]
    x = dpp_add<0x141>(x);   // row_half_mirror
    x = dpp_add<0x140>(x);   // row_mirror
    return x;
}

// ---------------------------------------------------------------------------
// Kernel 1: gather + fp32->bf16 convert + fused en_score + denom zero-init.
// (weight arrays no longer materialized — weights computed in-kernel now)
// ---------------------------------------------------------------------------
__global__ void gather_kernel(
    const float* __restrict__ zs,
    const float* __restrict__ W_en, const float* __restrict__ W_fr,
    const int* __restrict__ pos_en, const int* __restrict__ neg_en,
    const int* __restrict__ pos_fr, const int* __restrict__ neg_fr,
    const int* __restrict__ x_en,
    unsigned short* __restrict__ z_bf,
    unsigned short* __restrict__ E_en, unsigned short* __restrict__ E_fr,
    float* __restrict__ en_score,
    float* __restrict__ denom_en, float* __restrict__ denom_fr,
    int Pe, int Pf, int Lpe, int Lpf)
{
    int row  = blockIdx.x * 4 + (threadIdx.x >> 6);
    int lane = threadIdx.x & 63;
    const float* src = nullptr;
    unsigned short* dst = nullptr;
    bool zero = false;

    if (row < NTOK) {
        src = zs + (size_t)row * DDIM;
        dst = z_bf + (size_t)row * DDIM;
        if (lane == 0) { denom_en[row] = 0.0f; denom_fr[row] = 0.0f; }
    } else if (row < NTOK + Lpe) {
        int j = row - NTOK;
        int Le = Pe + NEGN;
        int idx = 0;
        if (j < Pe)      idx = pos_en[j];
        else if (j < Le) idx = neg_en[j - Pe];
        else             zero = true;
        src = W_en + (size_t)idx * DDIM;
        dst = E_en + (size_t)j * DDIM;
    } else if (row < NTOK + Lpe + Lpf) {
        int j = row - NTOK - Lpe;
        int Lf = Pf + NEGN;
        int idx = 0;
        if (j < Pf)      idx = pos_fr[j];
        else if (j < Lf) idx = neg_fr[j - Pf];
        else             zero = true;
        src = W_fr + (size_t)idx * DDIM;
        dst = E_fr + (size_t)j * DDIM;
    } else if (row < NTOK + Lpe + Lpf + NTOK) {
        // fused en_score: zs[j] . W_en[x_en[j]] in fp32, wave reduce
        int j = row - NTOK - Lpe - Lpf;
        int idx = x_en[j];
        float4 z = *(const float4*)(zs   + (size_t)j   * DDIM + lane * 4);
        float4 w = *(const float4*)(W_en + (size_t)idx * DDIM + lane * 4);
        float s = z.x * w.x + z.y * w.y + z.z * w.z + z.w * w.w;
        #pragma unroll
        for (int m = 32; m; m >>= 1) s += __shfl_xor(s, m);
        if (lane == 0) en_score[j] = s;
        return;
    } else {
        return;
    }

    int d = lane * 4;
    float4 v;
    if (zero) { v.x = v.y = v.z = v.w = 0.0f; }
    else      { v = *(const float4*)(src + d); }
    ushort4 o;
    o.x = f2bf(v.x); o.y = f2bf(v.y); o.z = f2bf(v.z); o.w = f2bf(v.w);
    *(ushort4*)(dst + d) = o;
}

// ---------------------------------------------------------------------------
// Kernel 2: fused denominators — BARRIER-FREE wave-private streaming GEMM.
// Block = 4 waves; each wave owns 64 m rows (shared, A in registers) x a
// PRIVATE 64-n column strip (block tile 64m x 256n, streamed over n).
// Each wave stages its own B chunk (64 rows x 32 halfs, 4 DMAs) into a
// private 4-slot LDS ring (chunk-major, conflict-free). Producer==consumer
// -> NO s_barrier anywhere; waves drift, MFMA/VALU overlap across waves.
// Loop vmcnt queue holds ONLY chunk DMAs (weights are computed, not loaded):
// stage(c+2) -> s_waitcnt vmcnt(8) waits exactly chunk c (c+1,c+2 in flight,
// ~2 chunk-rounds of flight time >> L2 latency).
// Frag layouts (HW-verified rounds 1-7, absmax 0.0):
//   A/B: lane holds row (lane&15), 8 k-halfs at (lane>>4)*8
//   C/D: n-col = lane&15, m-row = (lane>>4)*4 + reg
// ---------------------------------------------------------------------------
__global__ __launch_bounds__(256, 2) void expsum_stream(
    const unsigned short* __restrict__ A,   // z_bf [4096 x 256]
    const unsigned short* __restrict__ E,   // [Ltot x 256]
    const float* __restrict__ kep, const float* __restrict__ kfp,
    float* __restrict__ out_en, float* __restrict__ out_fr,
    int Pe, int Pf, int Lpe, int NT)        // NT = Ltot/256 n-tiles
{
    __shared__ __align__(16) unsigned short Bs[4][4][2048]; // [wave][slot][4KB]

    // XCD-pure slices: all blocks with lin%8==k stream slice k (L2-resident)
    int lin = blockIdx.y * 64 + blockIdx.x;
    int yb  = lin & 7;       // 0..7 stream slice
    int xb  = lin >> 3;      // 0..63 m-tile

    int t    = threadIdx.x;
    int lane = t & 63;
    int wave = t >> 6;
    int col  = lane & 15;
    int quad = lane >> 4;

    // kappas: load + pin BEFORE any DMA so the loop vmcnt queue stays pure
    float ke = kep[0], kf = kfp[0];
    asm volatile("" : "+v"(ke), "+v"(kf) : : "memory");

    // ---- A fragments in registers (one-time load; 64 m rows shared by waves)
    bf16x8 afr[4][8];
    {
        const unsigned short* Ap = A + ((size_t)(xb * 64 + col)) * DDIM + quad * 8;
        #pragma unroll
        for (int i = 0; i < 4; i++)
            #pragma unroll
            for (int c = 0; c < 8; c++)
                afr[i][c] = *(const bf16x8*)(Ap + (size_t)i * 16 * DDIM + c * 32);
    }

    float sums[4][4];
    #pragma unroll
    for (int i = 0; i < 4; i++)
        #pragma unroll
        for (int rr = 0; rr < 4; rr++) sums[i][rr] = 0.0f;
    float* curout = out_en;
    int outrow = xb * 64;

    int ntiles = (NT - yb + 7) >> 3;
    int C = ntiles * 8;
    unsigned short* myBs = &Bs[wave][0][0];

    // stage chunk c (global chunk index within this wave's stream)
    #define STAGE(c) do {                                                     \
        int tl_ = yb + (((c) >> 3) << 3);                                     \
        int kk_ = ((c) & 7) * 32;                                             \
        int ngb_ = tl_ * 256 + wave * 64;                                     \
        const unsigned short* g_ =                                            \
            E + (size_t)(ngb_ + col) * DDIM + kk_ + quad * 8;                 \
        unsigned short* l_ = myBs + ((c) & 3) * 2048;                         \
        gl_lds16(g_,                 l_);                                     \
        gl_lds16(g_ + 16 * DDIM,     l_ + 512);                               \
        gl_lds16(g_ + 32 * DDIM,     l_ + 1024);                              \
        gl_lds16(g_ + 48 * DDIM,     l_ + 1536);                              \
    } while (0)

    STAGE(0);
    STAGE(1);

    for (int s = 0; s < ntiles; s++) {
        int tl = yb + (s << 3);
        int nb = tl * 256;

        float* o = (nb >= Lpe) ? out_fr : out_en;
        if (o != curout) {
            // flush en sums at the en->fr boundary (stream is monotone);
            // the atomics are older than subsequent DMAs -> drained by the
            // next vmcnt wait (one-time cost per block).
            if (col == 0) {
                #pragma unroll
                for (int i = 0; i < 4; i++)
                    #pragma unroll
                    for (int rr = 0; rr < 4; rr++)
                        atomicAdd(curout + outrow + 16 * i + quad * 4 + rr, sums[i][rr]);
            }
            #pragma unroll
            for (int i = 0; i < 4; i++)
                #pragma unroll
                for (int rr = 0; rr < 4; rr++) sums[i][rr] = 0.0f;
            curout = o;
        }

        // arithmetic weights: n < P -> 1 ; n < P+NEGN -> kappa ; else 0 (pad)
        float wj[4];
        #pragma unroll
        for (int j = 0; j < 4; j++) {
            int ngl = nb + wave * 64 + 16 * j + col;
            if (nb < Lpe) {
                wj[j] = (ngl < Pe) ? 1.0f : ((ngl < Pe + NEGN) ? ke : 0.0f);
            } else {
                int nl = ngl - Lpe;
                wj[j] = (nl < Pf) ? 1.0f : ((nl < Pf + NEGN) ? kf : 0.0f);
            }
        }

        f32x4 acc[4][4];
        #pragma unroll
        for (int i = 0; i < 4; i++)
            #pragma unroll
            for (int j = 0; j < 4; j++)
                acc[i][j] = (f32x4){0.f, 0.f, 0.f, 0.f};

        #pragma unroll
        for (int k8 = 0; k8 < 8; k8++) {
            int c  = s * 8 + k8;
            int rb = c & 3;
            if (c + 2 < C) {
                STAGE(c + 2);
                wait_vmcnt8();      // chunk c resident; c+1,c+2 in flight
            } else if (c + 1 < C) {
                wait_vmcnt4();
            } else {
                wait_vmcnt0();
            }

            bf16x8 bfv[4];
            #pragma unroll
            for (int j = 0; j < 4; j++)
                bfv[j] = *(const bf16x8*)(myBs + rb * 2048 + j * 512 + quad * 128 + col * 8);
            #pragma unroll
            for (int j = 0; j < 4; j++)
                #pragma unroll
                for (int i = 0; i < 4; i++)
                    acc[i][j] = __builtin_amdgcn_mfma_f32_16x16x32_bf16(
                        afr[i][k8], bfv[j], acc[i][j], 0, 0, 0);
        }

        // per-tile epilogue: weighted exp, DPP-reduce over this wave's 64 n.
        // No barrier -> other waves' MFMAs overlap this VALU phase.
        #pragma unroll
        for (int i = 0; i < 4; i++)
            #pragma unroll
            for (int rr = 0; rr < 4; rr++) {
                float sv = wj[0] * __expf(acc[i][0][rr]) + wj[1] * __expf(acc[i][1][rr])
                         + wj[2] * __expf(acc[i][2][rr]) + wj[3] * __expf(acc[i][3][rr]);
                sums[i][rr] += red16(sv);
            }
    }
    #undef STAGE

    // final flush (all 4 waves accumulate into the same 64 m rows)
    if (col == 0) {
        #pragma unroll
        for (int i = 0; i < 4; i++)
            #pragma unroll
            for (int rr = 0; rr < 4; rr++)
                atomicAdd(curout + outrow + 16 * i + quad * 4 + rr, sums[i][rr]);
    }
}

// ---------------------------------------------------------------------------
// Kernel 3: fr alignment (per-batch 64x64 exp-sum, weight 1/denom_fr) with
// inline W_fr[x_fr] gather+convert for A and the final loss fused in.
// ---------------------------------------------------------------------------
__global__ __launch_bounds__(256) void expsum_gemm64_loss(
    const float* __restrict__ W_fr,         // [V_FR x 256] fp32
    const int* __restrict__ x_fr,           // [B*64]
    const unsigned short* __restrict__ Bm,  // z_bf  [B][64 x 256]
    const float* __restrict__ denom_fr,     // [B*64]
    const float* __restrict__ denom_en,     // [B*64]
    const float* __restrict__ en_score,     // [B*64]
    const float* __restrict__ en_mask,
    const float* __restrict__ fr_mask,
    float* __restrict__ outloss)            // [128]: en | fr
{
    __shared__ __align__(16) unsigned short lda[TM * LDT];
    __shared__ __align__(16) unsigned short ldb[TN * LDT];
    __shared__ float tbuf[64];

    int batch = blockIdx.x;
    const unsigned short* Bb = Bm + (size_t)batch * TN * DDIM;

    int t      = threadIdx.x;
    int srow   = t >> 2;
    int schunk = t & 3;
    int lane   = t & 63;
    int wave   = t >> 6;
    int col    = lane & 15;
    int quad   = lane >> 4;

    int aidx = x_fr[batch * 64 + srow];
    const float* Arow = W_fr + (size_t)aidx * DDIM;

    f32x4 acc0 = {0.f,0.f,0.f,0.f};
    f32x4 acc1 = {0.f,0.f,0.f,0.f};
    f32x4 acc2 = {0.f,0.f,0.f,0.f};
    f32x4 acc3 = {0.f,0.f,0.f,0.f};

    for (int kk = 0; kk < DDIM; kk += 32) {
        float4 f0 = *(const float4*)(Arow + kk + schunk * 8);
        float4 f1 = *(const float4*)(Arow + kk + schunk * 8 + 4);
        uint4 bv = *(const uint4*)(Bb + (size_t)srow * DDIM + kk + schunk * 8);
        ushort4 ua; ua.x = f2bf(f0.x); ua.y = f2bf(f0.y); ua.z = f2bf(f0.z); ua.w = f2bf(f0.w);
        ushort4 ub; ub.x = f2bf(f1.x); ub.y = f2bf(f1.y); ub.z = f2bf(f1.z); ub.w = f2bf(f1.w);
        __syncthreads();
        *(ushort4*)(lda + srow * LDT + schunk * 8)     = ua;
        *(ushort4*)(lda + srow * LDT + schunk * 8 + 4) = ub;
        *(uint4*)(ldb + srow * LDT + schunk * 8) = bv;
        __syncthreads();

        bf16x8 af = *(const bf16x8*)(lda + (wave * 16 + col) * LDT + quad * 8);
        bf16x8 b0 = *(const bf16x8*)(ldb + ( 0 + col) * LDT + quad * 8);
        bf16x8 b1 = *(const bf16x8*)(ldb + (16 + col) * LDT + quad * 8);
        bf16x8 b2 = *(const bf16x8*)(ldb + (32 + col) * LDT + quad * 8);
        bf16x8 b3 = *(const bf16x8*)(ldb + (48 + col) * LDT + quad * 8);
        acc0 = __builtin_amdgcn_mfma_f32_16x16x32_bf16(af, b0, acc0, 0, 0, 0);
        acc1 = __builtin_amdgcn_mfma_f32_16x16x32_bf16(af, b1, acc1, 0, 0, 0);
        acc2 = __builtin_amdgcn_mfma_f32_16x16x32_bf16(af, b2, acc2, 0, 0, 0);
        acc3 = __builtin_amdgcn_mfma_f32_16x16x32_bf16(af, b3, acc3, 0, 0, 0);
    }

    const float* db = denom_fr + batch * 64;
    float w0 = 1.0f / db[ 0 + col];
    float w1 = 1.0f / db[16 + col];
    float w2 = 1.0f / db[32 + col];
    float w3 = 1.0f / db[48 + col];

    float tot0 = w0 * __expf(acc0.x) + w1 * __expf(acc1.x) + w2 * __expf(acc2.x) + w3 * __expf(acc3.x);
    float tot1 = w0 * __expf(acc0.y) + w1 * __expf(acc1.y) + w2 * __expf(acc2.y) + w3 * __expf(acc3.y);
    float tot2 = w0 * __expf(acc0.z) + w1 * __expf(acc1.z) + w2 * __expf(acc2.z) + w3 * __expf(acc3.z);
    float tot3 = w0 * __expf(acc0.w) + w1 * __expf(acc1.w) + w2 * __expf(acc2.w) + w3 * __expf(acc3.w);

    #pragma unroll
    for (int m = 1; m < 16; m <<= 1) {
        tot0 += __shfl_xor(tot0, m);
        tot1 += __shfl_xor(tot1, m);
        tot2 += __shfl_xor(tot2, m);
        tot3 += __shfl_xor(tot3, m);
    }
    if (col == 0) {
        int base = wave * 16 + quad * 4;
        tbuf[base + 0] = tot0; tbuf[base + 1] = tot1;
        tbuf[base + 2] = tot2; tbuf[base + 3] = tot3;
    }
    __syncthreads();

    if (t < 64) {
        int i = batch * 64 + t;
        float a = (en_score[i] - __logf(denom_en[i])) * en_mask[i];
        float c = __logf(tbuf[t]) * fr_mask[i];
        #pragma unroll
        for (int m = 32; m; m >>= 1) { a += __shfl_xor(a, m); c += __shfl_xor(c, m); }
        if (t == 0) { outloss[batch] = a; outloss[64 + batch] = c; }
    }
}

extern "C" void kernel_launch(void* const* d_in, const int* in_sizes, int n_in,
                              void* d_out, int out_size, void* d_ws, size_t ws_size,
                              hipStream_t stream)
{
    const float* zs       = (const float*)d_in[0];
    const int*   x_en     = (const int*)d_in[1];
    const int*   x_fr     = (const int*)d_in[2];
    const float* en_mask  = (const float*)d_in[3];
    const float* fr_mask  = (const float*)d_in[4];
    const float* W_en     = (const float*)d_in[5];
    const float* W_fr     = (const float*)d_in[6];
    const int*   pos_en   = (const int*)d_in[7];
    const int*   neg_en   = (const int*)d_in[8];
    const int*   pos_fr   = (const int*)d_in[9];
    const int*   neg_fr   = (const int*)d_in[10];
    const float* kappa_en = (const float*)d_in[11];
    const float* kappa_fr = (const float*)d_in[12];

    int Pe  = in_sizes[7];
    int Pf  = in_sizes[9];
    int Lpe = (Pe + NEGN + 255) & ~255;   // 256-aligned n-tiles (no straddle)
    int Lpf = (Pf + NEGN + 255) & ~255;
    int Ltot = Lpe + Lpf;
    int NT   = Ltot / 256;

    char* w = (char*)d_ws;
    float* denom_en = (float*)w; w += NTOK * 4;
    float* denom_fr = (float*)w; w += NTOK * 4;
    float* en_score = (float*)w; w += NTOK * 4;
    unsigned short* z_bf  = (unsigned short*)w; w += (size_t)NTOK * DDIM * 2;
    unsigned short* E_all = (unsigned short*)w; w += (size_t)Ltot * DDIM * 2;

    int totrows = NTOK + Lpe + Lpf + NTOK;
    gather_kernel<<<(totrows + 3) / 4, 256, 0, stream>>>(
        zs, W_en, W_fr, pos_en, neg_en, pos_fr, neg_fr, x_en,
        z_bf, E_all, E_all + (size_t)Lpe * DDIM,
        en_score, denom_en, denom_fr, Pe, Pf, Lpe, Lpf);

    // fused denominators: barrier-free wave-private streaming GEMM
    expsum_stream<<<dim3(64, 8), 256, 0, stream>>>(
        z_bf, E_all, kappa_en, kappa_fr, denom_en, denom_fr, Pe, Pf, Lpe, NT);

    // fr alignment + inline W_fr gather + fused loss
    expsum_gemm64_loss<<<64, 256, 0, stream>>>(
        W_fr, x_fr, z_bf, denom_fr, denom_en, en_score, en_mask, fr_mask,
        (float*)d_out);
}

// Round 9
// 202.424 us; speedup vs baseline: 1.2293x; 1.2293x over previous
//
#include <hip/hip_runtime.h>

#define DDIM 256
#define NTOK 4096   // B*S = 64*64
#define NEGN 8192
// small 64x64 kernel (fr alignment)
#define TM 64
#define TN 64
#define LDT 40      // padded halfs per LDS row for the small kernel

typedef __attribute__((ext_vector_type(8))) short bf16x8;
typedef __attribute__((ext_vector_type(4))) float f32x4;

__device__ inline unsigned short f2bf(float f) {
    unsigned int u = __float_as_uint(f);
    unsigned int r = u + 0x7FFFu + ((u >> 16) & 1u);
    return (unsigned short)(r >> 16);
}

// global->LDS direct DMA, 16B/lane; LDS dest = wave-uniform base + lane*16.
__device__ inline void gl_lds16(const unsigned short* g, unsigned short* l) {
    __builtin_amdgcn_global_load_lds(
        reinterpret_cast<__attribute__((address_space(1))) unsigned int*>(
            reinterpret_cast<uintptr_t>(g)),
        reinterpret_cast<__attribute__((address_space(3))) unsigned int*>(
            reinterpret_cast<uintptr_t>(l)),
        16, 0, 0);
}

__device__ inline void wait_vmcnt2() { asm volatile("s_waitcnt vmcnt(2)" ::: "memory"); }
__device__ inline void wait_vmcnt1() { asm volatile("s_waitcnt vmcnt(1)" ::: "memory"); }
__device__ inline void wait_vmcnt0() { asm volatile("s_waitcnt vmcnt(0)" ::: "memory"); }
__device__ inline void raw_barrier() { asm volatile("s_barrier" ::: "memory"); }

// DPP 16-lane sum reduction — VALU only.
template<int CTRL>
__device__ inline float dpp_add(float x) {
    int v = __builtin_amdgcn_update_dpp(0, __float_as_int(x), CTRL, 0xF, 0xF, false);
    return x + __int_as_float(v);
}
__device__ inline float red16(float x) {
    x = dpp_add<0xB1>(x);    // quad_perm [1,0,3,2]
    x = dpp_add<0x4E>(x);    // quad_perm [2,3,0,1]
    x = dpp_add<0x141>(x);   // row_half_mirror
    x = dpp_add<0x140>(x);   // row_mirror
    return x;
}

// ---------------------------------------------------------------------------
// Kernel 1: gather + fp32->bf16 convert + fused en_score + denom zero-init.
// ---------------------------------------------------------------------------
__global__ void gather_kernel(
    const float* __restrict__ zs,
    const float* __restrict__ W_en, const float* __restrict__ W_fr,
    const int* __restrict__ pos_en, const int* __restrict__ neg_en,
    const int* __restrict__ pos_fr, const int* __restrict__ neg_fr,
    const int* __restrict__ x_en,
    unsigned short* __restrict__ z_bf,
    unsigned short* __restrict__ E_en, unsigned short* __restrict__ E_fr,
    float* __restrict__ en_score,
    float* __restrict__ denom_en, float* __restrict__ denom_fr,
    int Pe, int Pf, int Lpe, int Lpf)
{
    int row  = blockIdx.x * 4 + (threadIdx.x >> 6);
    int lane = threadIdx.x & 63;
    const float* src = nullptr;
    unsigned short* dst = nullptr;
    bool zero = false;

    if (row < NTOK) {
        src = zs + (size_t)row * DDIM;
        dst = z_bf + (size_t)row * DDIM;
        if (lane == 0) { denom_en[row] = 0.0f; denom_fr[row] = 0.0f; }
    } else if (row < NTOK + Lpe) {
        int j = row - NTOK;
        int Le = Pe + NEGN;
        int idx = 0;
        if (j < Pe)      idx = pos_en[j];
        else if (j < Le) idx = neg_en[j - Pe];
        else             zero = true;
        src = W_en + (size_t)idx * DDIM;
        dst = E_en + (size_t)j * DDIM;
    } else if (row < NTOK + Lpe + Lpf) {
        int j = row - NTOK - Lpe;
        int Lf = Pf + NEGN;
        int idx = 0;
        if (j < Pf)      idx = pos_fr[j];
        else if (j < Lf) idx = neg_fr[j - Pf];
        else             zero = true;
        src = W_fr + (size_t)idx * DDIM;
        dst = E_fr + (size_t)j * DDIM;
    } else if (row < NTOK + Lpe + Lpf + NTOK) {
        // fused en_score: zs[j] . W_en[x_en[j]] in fp32, wave reduce
        int j = row - NTOK - Lpe - Lpf;
        int idx = x_en[j];
        float4 z = *(const float4*)(zs   + (size_t)j   * DDIM + lane * 4);
        float4 w = *(const float4*)(W_en + (size_t)idx * DDIM + lane * 4);
        float s = z.x * w.x + z.y * w.y + z.z * w.z + z.w * w.w;
        #pragma unroll
        for (int m = 32; m; m >>= 1) s += __shfl_xor(s, m);
        if (lane == 0) en_score[j] = s;
        return;
    } else {
        return;
    }

    int d = lane * 4;
    float4 v;
    if (zero) { v.x = v.y = v.z = v.w = 0.0f; }
    else      { v = *(const float4*)(src + d); }
    ushort4 o;
    o.x = f2bf(v.x); o.y = f2bf(v.y); o.z = f2bf(v.z); o.w = f2bf(v.w);
    *(ushort4*)(dst + d) = o;
}

// ---------------------------------------------------------------------------
// Kernel 2: fused denominators — R7 sync skeleton, rebalanced 256m x 64n.
// Block = 4 waves, each owning 64 distinct m rows (A in registers, whole K);
// the block shares ONE 64-n strip. Per 32-k chunk: each wave stages its own
// 16-row sub-tile with ONE global_load_lds (4 DMAs/chunk/block — half of R7)
// into a shared 4-slot LDS ring (chunk-major, conflict-free). Sync per chunk:
// STAGE(c+2) -> s_waitcnt vmcnt(2) [chunk c resident; c+1,c+2 in flight] ->
// raw s_barrier (no compiler vmcnt(0) drain) -> 4 ds_read_b128 -> 16 MFMAs.
// The vmcnt queue holds ONLY chunk DMAs: weights are computed arithmetically
// (kappas pre-loaded and pinned), so no over-wait on unrelated loads.
// Column-reduction deferred: per-tile epilogue just accumulates per-lane
// weighted exps; one red16 + atomic at stream end / en-fr boundary.
// Frag layouts (HW-verified rounds 1-8, absmax 0.0):
//   A/B: lane holds row (lane&15), 8 k-halfs at (lane>>4)*8
//   C/D: n-col = lane&15, m-row = (lane>>4)*4 + reg
// ---------------------------------------------------------------------------
__global__ __launch_bounds__(256, 2) void expsum_stream(
    const unsigned short* __restrict__ A,   // z_bf [4096 x 256]
    const unsigned short* __restrict__ E,   // [Ltot x 256]
    const float* __restrict__ kep, const float* __restrict__ kfp,
    float* __restrict__ out_en, float* __restrict__ out_fr,
    int Pe, int Pf, int Lpe, int NT)        // NT = Ltot/64 n-tiles
{
    __shared__ __align__(16) unsigned short Bs[4][2048]; // 4-slot ring, 4KB each

    // 512 blocks: xcd = lin&7, m-tile xb = (lin>>3)&15, slice = xcd + 8*(lin>>7)
    // XCD k streams only tiles ≡ k (mod 8) -> 1/8 of E resident in its L2.
    int lin = blockIdx.y * 64 + blockIdx.x;
    int xcd = lin & 7;
    int xb  = (lin >> 3) & 15;
    int sl  = xcd + 8 * (lin >> 7);    // 0..31; tiles {sl, sl+32, ...}

    int t    = threadIdx.x;
    int lane = t & 63;
    int wave = t >> 6;
    int col  = lane & 15;
    int quad = lane >> 4;

    // kappas: load + pin BEFORE any DMA so the loop vmcnt queue stays pure
    float ke = kep[0], kf = kfp[0];
    asm volatile("" : "+v"(ke), "+v"(kf) : : "memory");

    // ---- A fragments in registers (one-time load; wave owns 64 m rows)
    bf16x8 afr[4][8];
    {
        const unsigned short* Ap =
            A + ((size_t)(xb * 256 + wave * 64 + col)) * DDIM + quad * 8;
        #pragma unroll
        for (int i = 0; i < 4; i++)
            #pragma unroll
            for (int c = 0; c < 8; c++)
                afr[i][c] = *(const bf16x8*)(Ap + (size_t)i * 16 * DDIM + c * 32);
    }

    float sums[4][4];
    #pragma unroll
    for (int i = 0; i < 4; i++)
        #pragma unroll
        for (int rr = 0; rr < 4; rr++) sums[i][rr] = 0.0f;
    float* curout = out_en;
    int outrow = xb * 256 + wave * 64;

    int ntiles = (NT - sl + 31) >> 5;
    int C = ntiles * 8;

    // stage chunk c: this wave's 16-row sub-tile, one DMA
    #define STAGE(c) do {                                                     \
        int tl_ = sl + (((c) >> 3) << 5);                                     \
        int kk_ = ((c) & 7) * 32;                                             \
        const unsigned short* g_ =                                            \
            E + (size_t)(tl_ * 64 + wave * 16 + col) * DDIM + kk_ + quad * 8; \
        gl_lds16(g_, &Bs[(c) & 3][wave * 512]);                               \
    } while (0)

    STAGE(0);
    STAGE(1);

    for (int s = 0; s < ntiles; s++) {
        int tl = sl + (s << 5);
        int nb = tl * 64;

        float* o = (nb >= Lpe) ? out_fr : out_en;
        if (o != curout) {
            // flush en sums at the en->fr boundary (stream is monotone);
            // one-time vmcnt-queue pollution, drained by the next wait.
            #pragma unroll
            for (int i = 0; i < 4; i++)
                #pragma unroll
                for (int rr = 0; rr < 4; rr++) {
                    float v = red16(sums[i][rr]);
                    if (col == 0)
                        atomicAdd(curout + outrow + 16 * i + quad * 4 + rr, v);
                    sums[i][rr] = 0.0f;
                }
            curout = o;
        }

        // arithmetic weights: n < P -> 1 ; n < P+NEGN -> kappa ; else 0 (pad)
        float wj[4];
        #pragma unroll
        for (int j = 0; j < 4; j++) {
            int ngl = nb + 16 * j + col;
            if (nb < Lpe) {
                wj[j] = (ngl < Pe) ? 1.0f : ((ngl < Pe + NEGN) ? ke : 0.0f);
            } else {
                int nl = ngl - Lpe;
                wj[j] = (nl < Pf) ? 1.0f : ((nl < Pf + NEGN) ? kf : 0.0f);
            }
        }

        f32x4 acc[4][4];
        #pragma unroll
        for (int i = 0; i < 4; i++)
            #pragma unroll
            for (int j = 0; j < 4; j++)
                acc[i][j] = (f32x4){0.f, 0.f, 0.f, 0.f};

        #pragma unroll
        for (int k8 = 0; k8 < 8; k8++) {
            int c  = s * 8 + k8;
            int rb = c & 3;
            if (c + 2 < C) {
                STAGE(c + 2);
                wait_vmcnt2();      // chunk c resident; c+1,c+2 in flight
            } else if (c + 1 < C) {
                wait_vmcnt1();
            } else {
                wait_vmcnt0();
            }
            raw_barrier();          // no compiler-inserted vmcnt(0) drain

            bf16x8 bfv[4];
            #pragma unroll
            for (int j = 0; j < 4; j++)
                bfv[j] = *(const bf16x8*)(&Bs[rb][j * 512 + quad * 128 + col * 8]);
            #pragma unroll
            for (int j = 0; j < 4; j++)
                #pragma unroll
                for (int i = 0; i < 4; i++)
                    acc[i][j] = __builtin_amdgcn_mfma_f32_16x16x32_bf16(
                        afr[i][k8], bfv[j], acc[i][j], 0, 0, 0);
        }

        // per-tile epilogue: weighted exp only; column reduction deferred.
        #pragma unroll
        for (int i = 0; i < 4; i++)
            #pragma unroll
            for (int rr = 0; rr < 4; rr++) {
                sums[i][rr] += wj[0] * __expf(acc[i][0][rr])
                             + wj[1] * __expf(acc[i][1][rr])
                             + wj[2] * __expf(acc[i][2][rr])
                             + wj[3] * __expf(acc[i][3][rr]);
            }
    }
    #undef STAGE

    // final flush: one deferred 16-lane reduction per acc entry
    #pragma unroll
    for (int i = 0; i < 4; i++)
        #pragma unroll
        for (int rr = 0; rr < 4; rr++) {
            float v = red16(sums[i][rr]);
            if (col == 0)
                atomicAdd(curout + outrow + 16 * i + quad * 4 + rr, v);
        }
}

// ---------------------------------------------------------------------------
// Kernel 3: fr alignment (per-batch 64x64 exp-sum, weight 1/denom_fr) with
// inline W_fr[x_fr] gather+convert for A and the final loss fused in.
// ---------------------------------------------------------------------------
__global__ __launch_bounds__(256) void expsum_gemm64_loss(
    const float* __restrict__ W_fr,         // [V_FR x 256] fp32
    const int* __restrict__ x_fr,           // [B*64]
    const unsigned short* __restrict__ Bm,  // z_bf  [B][64 x 256]
    const float* __restrict__ denom_fr,     // [B*64]
    const float* __restrict__ denom_en,     // [B*64]
    const float* __restrict__ en_score,     // [B*64]
    const float* __restrict__ en_mask,
    const float* __restrict__ fr_mask,
    float* __restrict__ outloss)            // [128]: en | fr
{
    __shared__ __align__(16) unsigned short lda[TM * LDT];
    __shared__ __align__(16) unsigned short ldb[TN * LDT];
    __shared__ float tbuf[64];

    int batch = blockIdx.x;
    const unsigned short* Bb = Bm + (size_t)batch * TN * DDIM;

    int t      = threadIdx.x;
    int srow   = t >> 2;
    int schunk = t & 3;
    int lane   = t & 63;
    int wave   = t >> 6;
    int col    = lane & 15;
    int quad   = lane >> 4;

    int aidx = x_fr[batch * 64 + srow];
    const float* Arow = W_fr + (size_t)aidx * DDIM;

    f32x4 acc0 = {0.f,0.f,0.f,0.f};
    f32x4 acc1 = {0.f,0.f,0.f,0.f};
    f32x4 acc2 = {0.f,0.f,0.f,0.f};
    f32x4 acc3 = {0.f,0.f,0.f,0.f};

    for (int kk = 0; kk < DDIM; kk += 32) {
        float4 f0 = *(const float4*)(Arow + kk + schunk * 8);
        float4 f1 = *(const float4*)(Arow + kk + schunk * 8 + 4);
        uint4 bv = *(const uint4*)(Bb + (size_t)srow * DDIM + kk + schunk * 8);
        ushort4 ua; ua.x = f2bf(f0.x); ua.y = f2bf(f0.y); ua.z = f2bf(f0.z); ua.w = f2bf(f0.w);
        ushort4 ub; ub.x = f2bf(f1.x); ub.y = f2bf(f1.y); ub.z = f2bf(f1.z); ub.w = f2bf(f1.w);
        __syncthreads();
        *(ushort4*)(lda + srow * LDT + schunk * 8)     = ua;
        *(ushort4*)(lda + srow * LDT + schunk * 8 + 4) = ub;
        *(uint4*)(ldb + srow * LDT + schunk * 8) = bv;
        __syncthreads();

        bf16x8 af = *(const bf16x8*)(lda + (wave * 16 + col) * LDT + quad * 8);
        bf16x8 b0 = *(const bf16x8*)(ldb + ( 0 + col) * LDT + quad * 8);
        bf16x8 b1 = *(const bf16x8*)(ldb + (16 + col) * LDT + quad * 8);
        bf16x8 b2 = *(const bf16x8*)(ldb + (32 + col) * LDT + quad * 8);
        bf16x8 b3 = *(const bf16x8*)(ldb + (48 + col) * LDT + quad * 8);
        acc0 = __builtin_amdgcn_mfma_f32_16x16x32_bf16(af, b0, acc0, 0, 0, 0);
        acc1 = __builtin_amdgcn_mfma_f32_16x16x32_bf16(af, b1, acc1, 0, 0, 0);
        acc2 = __builtin_amdgcn_mfma_f32_16x16x32_bf16(af, b2, acc2, 0, 0, 0);
        acc3 = __builtin_amdgcn_mfma_f32_16x16x32_bf16(af, b3, acc3, 0, 0, 0);
    }

    const float* db = denom_fr + batch * 64;
    float w0 = 1.0f / db[ 0 + col];
    float w1 = 1.0f / db[16 + col];
    float w2 = 1.0f / db[32 + col];
    float w3 = 1.0f / db[48 + col];

    float tot0 = w0 * __expf(acc0.x) + w1 * __expf(acc1.x) + w2 * __expf(acc2.x) + w3 * __expf(acc3.x);
    float tot1 = w0 * __expf(acc0.y) + w1 * __expf(acc1.y) + w2 * __expf(acc2.y) + w3 * __expf(acc3.y);
    float tot2 = w0 * __expf(acc0.z) + w1 * __expf(acc1.z) + w2 * __expf(acc2.z) + w3 * __expf(acc3.z);
    float tot3 = w0 * __expf(acc0.w) + w1 * __expf(acc1.w) + w2 * __expf(acc2.w) + w3 * __expf(acc3.w);

    #pragma unroll
    for (int m = 1; m < 16; m <<= 1) {
        tot0 += __shfl_xor(tot0, m);
        tot1 += __shfl_xor(tot1, m);
        tot2 += __shfl_xor(tot2, m);
        tot3 += __shfl_xor(tot3, m);
    }
    if (col == 0) {
        int base = wave * 16 + quad * 4;
        tbuf[base + 0] = tot0; tbuf[base + 1] = tot1;
        tbuf[base + 2] = tot2; tbuf[base + 3] = tot3;
    }
    __syncthreads();

    if (t < 64) {
        int i = batch * 64 + t;
        float a = (en_score[i] - __logf(denom_en[i])) * en_mask[i];
        float c = __logf(tbuf[t]) * fr_mask[i];
        #pragma unroll
        for (int m = 32; m; m >>= 1) { a += __shfl_xor(a, m); c += __shfl_xor(c, m); }
        if (t == 0) { outloss[batch] = a; outloss[64 + batch] = c; }
    }
}

extern "C" void kernel_launch(void* const* d_in, const int* in_sizes, int n_in,
                              void* d_out, int out_size, void* d_ws, size_t ws_size,
                              hipStream_t stream)
{
    const float* zs       = (const float*)d_in[0];
    const int*   x_en     = (const int*)d_in[1];
    const int*   x_fr     = (const int*)d_in[2];
    const float* en_mask  = (const float*)d_in[3];
    const float* fr_mask  = (const float*)d_in[4];
    const float* W_en     = (const float*)d_in[5];
    const float* W_fr     = (const float*)d_in[6];
    const int*   pos_en   = (const int*)d_in[7];
    const int*   neg_en   = (const int*)d_in[8];
    const int*   pos_fr   = (const int*)d_in[9];
    const int*   neg_fr   = (const int*)d_in[10];
    const float* kappa_en = (const float*)d_in[11];
    const float* kappa_fr = (const float*)d_in[12];

    int Pe  = in_sizes[7];
    int Pf  = in_sizes[9];
    int Lpe = (Pe + NEGN + 63) & ~63;     // 64-aligned n-tiles (no straddle)
    int Lpf = (Pf + NEGN + 63) & ~63;
    int Ltot = Lpe + Lpf;
    int NT   = Ltot / 64;

    char* w = (char*)d_ws;
    float* denom_en = (float*)w; w += NTOK * 4;
    float* denom_fr = (float*)w; w += NTOK * 4;
    float* en_score = (float*)w; w += NTOK * 4;
    unsigned short* z_bf  = (unsigned short*)w; w += (size_t)NTOK * DDIM * 2;
    unsigned short* E_all = (unsigned short*)w; w += (size_t)Ltot * DDIM * 2;

    int totrows = NTOK + Lpe + Lpf + NTOK;
    gather_kernel<<<(totrows + 3) / 4, 256, 0, stream>>>(
        zs, W_en, W_fr, pos_en, neg_en, pos_fr, neg_fr, x_en,
        z_bf, E_all, E_all + (size_t)Lpe * DDIM,
        en_score, denom_en, denom_fr, Pe, Pf, Lpe, Lpf);

    // fused denominators: shared staging, raw barrier, pure vmcnt queue
    expsum_stream<<<dim3(64, 8), 256, 0, stream>>>(
        z_bf, E_all, kappa_en, kappa_fr, denom_en, denom_fr, Pe, Pf, Lpe, NT);

    // fr alignment + inline W_fr gather + fused loss
    expsum_gemm64_loss<<<64, 256, 0, stream>>>(
        W_fr, x_fr, z_bf, denom_fr, denom_en, en_score, en_mask, fr_mask,
        (float*)d_out);
}